// Round 1
// baseline (397.603 us; speedup 1.0000x reference)
//
#include <hip/hip_runtime.h>
#include <math.h>

// ---------------- static problem structure (LMAX=4, taus=16) ----------------
#define NTRI 42
#define NCH  10752          // total channels over all l
#define B_SZ 256
#define FF_TOT 15073280     // total complex elements of FF

// triples sorted by (l, l1, l2)
__constant__ int TL[NTRI]  = {0,0,0,0,0, 1,1,1,1,1,1,1,1, 2,2,2,2,2,2,2,2,2,2, 3,3,3,3,3,3,3,3,3,3, 4,4,4,4,4,4,4,4,4};
__constant__ int TL1[NTRI] = {0,1,2,3,4, 1,1,2,2,3,3,4,4, 1,2,2,2,3,3,3,4,4,4, 2,2,3,3,3,3,4,4,4,4, 2,3,3,3,4,4,4,4,4};
__constant__ int TL2[NTRI] = {0,1,2,3,4, 0,1,1,2,2,3,3,4, 1,0,1,2,1,2,3,2,3,4, 1,2,0,1,2,3,1,2,3,4, 2,1,2,3,0,1,2,3,4};
__constant__ int LTR[NTRI] = {0,1,2,3,4, 0,1,2,3,4,5,6,7, 0,1,2,3,4,5,6,7,8,9, 0,1,2,3,4,5,6,7,8,9, 0,1,2,3,4,5,6,7,8};

// per-l constants
__constant__ int KLc[5]     = {1280,2048,2560,2560,2304};   // t_FF[l]
__constant__ int GBASEc[5]  = {0,1280,3328,5888,8448};      // channel base
__constant__ int FFBASEc[5] = {0,327680,1900544,5177344,9764864}; // FF complex base
__constant__ int ROFFc[5]   = {0,16,64,144,256};            // row offset in 400-row input/output

// compile-time copies for templated matmul
constexpr int KL_t[5]     = {1280,2048,2560,2560,2304};
constexpr int GBASE_t[5]  = {0,1280,3328,5888,8448};
constexpr int FFBASE_t[5] = {0,327680,1900544,5177344,9764864};
constexpr int ROFF_t[5]   = {0,16,64,144,256};
constexpr int WOFF_t[5]   = {0,20480,53248,94208,135168};   // complex offset into W

// ---------------- device globals ----------------
__device__ float2 g_FF[FF_TOT];        // 120.6 MB intermediate
__device__ float  g_varsum[NCH];
__device__ float  g_inv[NCH];
__device__ int    g_cgpq[NTRI*81];     // (p<<4)|q
__device__ float  g_cgc[NTRI*81];
__device__ int    g_mstart[NTRI][10];  // entry ranges per m (sorted by m)

// ---------------- CG coefficient (exact reference formula, fp64) ----------------
__device__ double dfact(int n){ double r=1.0; for(int i=2;i<=n;i++) r*=(double)i; return r; }

__device__ double cg_coef(int j1,int m1,int j2,int m2,int j,int m){
    if (m1+m2!=m) return 0.0;
    double pref = sqrt((2.0*j+1.0)*dfact(j+j1-j2)*dfact(j-j1+j2)*dfact(j1+j2-j)/dfact(j1+j2+j+1));
    pref *= sqrt(dfact(j+m)*dfact(j-m)*dfact(j1-m1)*dfact(j1+m1)*dfact(j2-m2)*dfact(j2+m2));
    double s=0.0;
    for(int k=0;k<=j1+j2-j;k++){
        int a=j1-m1-k, bb=j2+m2-k, c=j-j2+m1+k, d=j-j1-m2+k;
        if(a<0||bb<0||c<0||d<0) continue;
        double term = 1.0/(dfact(k)*dfact(j1+j2-j-k)*dfact(a)*dfact(bb)*dfact(c)*dfact(d));
        s += (k&1)? -term : term;
    }
    return pref*s;
}

// ---------------- kernel 1: init (zero varsum, build CG tables) ----------------
__global__ void k_init(){
    int t = threadIdx.x;
    for(int i=t;i<NCH;i+=blockDim.x) g_varsum[i]=0.f;
    if(t<NTRI){
        int l=TL[t], l1=TL1[t], l2=TL2[t];
        int cnt=0;
        for(int m=-l;m<=l;m++){
            g_mstart[t][m+l]=cnt;
            for(int m1=-l1;m1<=l1;m1++){
                int m2=m-m1;
                if(m2<-l2||m2>l2) continue;
                double c=cg_coef(l1,m1,l2,m2,l,m);
                if(c!=0.0){
                    g_cgpq[t*81+cnt]=((m1+l1)<<4)|(m2+l2);
                    g_cgc[t*81+cnt]=(float)c;
                    cnt++;
                }
            }
        }
        g_mstart[t][2*l+1]=cnt;
    }
}

// ---------------- kernel 2: CG tensor product -> FF + variance sums ----------------
// grid (42, 256): blockIdx.x = triple, blockIdx.y = b.  256 threads = (i,j) pair.
__global__ void k_cg(const float2* __restrict__ Fs){
    const int tr=blockIdx.x, b=blockIdx.y, t=threadIdx.x;
    const int l=TL[tr], l1=TL1[tr], l2=TL2[tr];
    const int nm=2*l+1, n1=2*l1+1, n2=2*l2+1;
    const int K=KLc[l];
    const int chan = LTR[tr]*256 + t;          // channel within l-group

    __shared__ float2 As[16*9];
    __shared__ float2 Bs[16*9];
    __shared__ float  sC[81];
    __shared__ int    sPQ[81];

    const int cnt = g_mstart[tr][nm];
    if(t<16*n1) As[t]=Fs[b*400 + ROFFc[l1] + t];
    if(t<16*n2) Bs[t]=Fs[b*400 + ROFFc[l2] + t];
    if(t<cnt){ sC[t]=g_cgc[tr*81+t]; sPQ[t]=g_cgpq[tr*81+t]; }
    __syncthreads();

    const int i=t>>4, j=t&15;
    const float2* Ai=&As[i*n1];
    const float2* Bj=&Bs[j*n2];

    float norm2=0.f;
    const int ffb = FFBASEc[l] + (b*nm)*K + chan;
    for(int mi=0;mi<nm;mi++){
        float aR=0.f, aI=0.f;
        const int e1=g_mstart[tr][mi+1];
        for(int e=g_mstart[tr][mi]; e<e1; e++){
            const int pq=sPQ[e]; const float c=sC[e];
            const float2 av=Ai[pq>>4], bv=Bj[pq&15];
            const float pr = av.x*bv.x - av.y*bv.y;
            const float pi = av.x*bv.y + av.y*bv.x;
            aR=fmaf(c,pr,aR); aI=fmaf(c,pi,aI);
        }
        g_FF[ffb + mi*K] = make_float2(aR,aI);
        norm2 = fmaf(aR,aR,norm2);
        norm2 = fmaf(aI,aI,norm2);
    }
    atomicAdd(&g_varsum[GBASEc[l]+chan], norm2);
}

// ---------------- kernel 3: finalize inv scale ----------------
__global__ void k_inv(){
    int c = blockIdx.x*256 + threadIdx.x;
    if(c>=NCH) return;
    int l = (c<1280)?0:(c<3328)?1:(c<5888)?2:(c<8448)?3:4;
    float denom = 256.0f*(float)(2*l+1);
    float v = g_varsum[c]/denom;
    g_inv[c] = 1.0f/(sqrtf(v)+1e-5f);
}

// ---------------- kernel 4: complex weight matmul (normalization folded into x) ----
// grid (5, 256): blockIdx.x = l, blockIdx.y = b.  256 threads = (o=t>>4, sub=t&15).
template<int L>
__device__ void mm_body(const float2* __restrict__ W2, float2* __restrict__ out,
                        int b, int t, float2* sh){
    constexpr int NM = 2*L+1;
    constexpr int K  = KL_t[L];
    constexpr int WO = WOFF_t[L];
    constexpr int FB = FFBASE_t[L];
    constexpr int GB = GBASE_t[L];
    constexpr int RO = ROFF_t[L];
    const int o=t>>4, sub=t&15;

    float2 acc[NM];
    #pragma unroll
    for(int m=0;m<NM;m++) acc[m]=make_float2(0.f,0.f);

    for(int c0=0;c0<K;c0+=256){
        // stage x-tile (256 channels x NM m's), normalization applied here
        const float invv = g_inv[GB + c0 + t];
        #pragma unroll
        for(int m=0;m<NM;m++){
            float2 v = g_FF[FB + (b*NM+m)*K + c0 + t];
            sh[m*256+t] = make_float2(v.x*invv, v.y*invv);
        }
        __syncthreads();
        #pragma unroll
        for(int k=0;k<16;k++){
            const int c2 = sub + (k<<4);      // strided: conflict-free LDS banks
            const float2 w = W2[WO + o*K + c0 + c2];
            #pragma unroll
            for(int m=0;m<NM;m++){
                const float2 x = sh[m*256+c2];
                acc[m].x = fmaf(w.x,x.x, fmaf(-w.y,x.y, acc[m].x));
                acc[m].y = fmaf(w.x,x.y, fmaf( w.y,x.x, acc[m].y));
            }
        }
        __syncthreads();
    }

    // reduce the 16 sub-partials per (o,m)
    #pragma unroll
    for(int m=0;m<NM;m++) sh[(m*16+o)*16+sub]=acc[m];
    __syncthreads();
    if(t<16*NM){
        const int o2=t/NM, m2=t%NM;
        float2 s=make_float2(0.f,0.f);
        for(int ss=0;ss<16;ss++){
            float2 v=sh[(m2*16+o2)*16+ss];
            s.x+=v.x; s.y+=v.y;
        }
        out[b*400 + RO + o2*NM + m2] = s;
    }
}

__global__ void __launch_bounds__(256) k_mm(const float2* __restrict__ W2,
                                            float2* __restrict__ out){
    __shared__ float2 sh[9*256];
    const int b=blockIdx.y, t=threadIdx.x;
    switch(blockIdx.x){
        case 0: mm_body<0>(W2,out,b,t,sh); break;
        case 1: mm_body<1>(W2,out,b,t,sh); break;
        case 2: mm_body<2>(W2,out,b,t,sh); break;
        case 3: mm_body<3>(W2,out,b,t,sh); break;
        case 4: mm_body<4>(W2,out,b,t,sh); break;
    }
}

// ---------------- launcher ----------------
extern "C" void kernel_launch(void* const* d_in, const int* in_sizes, int n_in,
                              void* d_out, int out_size, void* d_ws, size_t ws_size,
                              hipStream_t stream){
    const float2* Fs = (const float2*)d_in[0];   // [256,400,2] fp32
    const float2* W  = (const float2*)d_in[1];   // [172032,2]  fp32
    float2* out = (float2*)d_out;                // [256,400,2] fp32

    k_init<<<1,256,0,stream>>>();
    k_cg <<<dim3(NTRI,B_SZ),256,0,stream>>>(Fs);
    k_inv<<<dim3((NCH+255)/256),256,0,stream>>>();
    k_mm <<<dim3(5,B_SZ),256,0,stream>>>(W,out);
}

// Round 2
// 160.057 us; speedup vs baseline: 2.4841x; 2.4841x over previous
//
#include <hip/hip_runtime.h>
#include <math.h>

// ---------------- static problem structure (LMAX=4, taus=16) ----------------
#define NTRI 42
#define NCH  10752          // total channels over all l
#define B_SZ 256
#define FF_TOT 15073280     // total complex elements of FF

// triples sorted by (l, l1, l2)
__constant__ int TL[NTRI]  = {0,0,0,0,0, 1,1,1,1,1,1,1,1, 2,2,2,2,2,2,2,2,2,2, 3,3,3,3,3,3,3,3,3,3, 4,4,4,4,4,4,4,4,4};
__constant__ int TL1[NTRI] = {0,1,2,3,4, 1,1,2,2,3,3,4,4, 1,2,2,2,3,3,3,4,4,4, 2,2,3,3,3,3,4,4,4,4, 2,3,3,3,4,4,4,4,4};
__constant__ int TL2[NTRI] = {0,1,2,3,4, 0,1,1,2,2,3,3,4, 1,0,1,2,1,2,3,2,3,4, 1,2,0,1,2,3,1,2,3,4, 2,1,2,3,0,1,2,3,4};
__constant__ int LTR[NTRI] = {0,1,2,3,4, 0,1,2,3,4,5,6,7, 0,1,2,3,4,5,6,7,8,9, 0,1,2,3,4,5,6,7,8,9, 0,1,2,3,4,5,6,7,8};

// per-l constants
__constant__ int KLc[5]     = {1280,2048,2560,2560,2304};   // t_FF[l]
__constant__ int GBASEc[5]  = {0,1280,3328,5888,8448};      // channel base
__constant__ int FFBASEc[5] = {0,327680,1900544,5177344,9764864}; // FF complex base
__constant__ int ROFFc[5]   = {0,16,64,144,256};            // row offset in 400-row input/output

// compile-time copies for templated matmul
constexpr int KL_t[5]     = {1280,2048,2560,2560,2304};
constexpr int GBASE_t[5]  = {0,1280,3328,5888,8448};
constexpr int FFBASE_t[5] = {0,327680,1900544,5177344,9764864};
constexpr int ROFF_t[5]   = {0,16,64,144,256};
constexpr int WOFF_t[5]   = {0,20480,53248,94208,135168};   // complex offset into W

// ---------------- device globals ----------------
__device__ float2 g_FF[FF_TOT];        // 120.6 MB intermediate
__device__ float  g_varsum[NCH];
__device__ float  g_inv[NCH];
// dense CG table: slot = mi*n1 + p, value = CG coef (0 if invalid pair).
// B-index is analytic: q = mi - p + (l1+l2-l).
__device__ float  g_cgcD[NTRI][81];

// ---------------- CG coefficient (exact reference formula, fp64) ----------------
__device__ double dfact(int n){ double r=1.0; for(int i=2;i<=n;i++) r*=(double)i; return r; }

__device__ double cg_coef(int j1,int m1,int j2,int m2,int j,int m){
    if (m1+m2!=m) return 0.0;
    double pref = sqrt((2.0*j+1.0)*dfact(j+j1-j2)*dfact(j-j1+j2)*dfact(j1+j2-j)/dfact(j1+j2+j+1));
    pref *= sqrt(dfact(j+m)*dfact(j-m)*dfact(j1-m1)*dfact(j1+m1)*dfact(j2-m2)*dfact(j2+m2));
    double s=0.0;
    for(int k=0;k<=j1+j2-j;k++){
        int a=j1-m1-k, bb=j2+m2-k, c=j-j2+m1+k, d=j-j1-m2+k;
        if(a<0||bb<0||c<0||d<0) continue;
        double term = 1.0/(dfact(k)*dfact(j1+j2-j-k)*dfact(a)*dfact(bb)*dfact(c)*dfact(d));
        s += (k&1)? -term : term;
    }
    return pref*s;
}

// ---------------- kernel 1: init — one thread per CG coefficient ----------------
// grid (NTRI) x 128: block tr builds triple tr's dense table; whole grid zeroes varsum.
__global__ void k_init(){
    const int tr = blockIdx.x, t = threadIdx.x;
    for(int i = blockIdx.x*blockDim.x + t; i < NCH; i += gridDim.x*blockDim.x)
        g_varsum[i] = 0.f;
    const int l=TL[tr], l1=TL1[tr], l2=TL2[tr];
    const int nm=2*l+1, n1=2*l1+1;
    if(t < nm*n1){
        const int mi = t / n1, p = t % n1;
        const int m = mi - l, m1 = p - l1, m2 = m - m1;
        float c = 0.f;
        if(m2 >= -l2 && m2 <= l2) c = (float)cg_coef(l1,m1,l2,m2,l,m);
        g_cgcD[tr][t] = c;
    }
}

// ---------------- kernel 2: CG tensor product -> FF + variance sums ----------------
// grid (42, 256): blockIdx.x = triple, blockIdx.y = b.  256 threads = (i,j) pair.
__global__ void k_cg(const float2* __restrict__ Fs){
    const int tr=blockIdx.x, b=blockIdx.y, t=threadIdx.x;
    const int l=TL[tr], l1=TL1[tr], l2=TL2[tr];
    const int nm=2*l+1, n1=2*l1+1, n2=2*l2+1;
    const int K=KLc[l];
    const int chan = LTR[tr]*256 + t;          // channel within l-group
    const int d = l1 + l2 - l;                 // q = mi - p + d

    __shared__ float2 As[16*9];
    __shared__ float2 Bs[16*9];
    __shared__ float  sC[81];

    if(t<16*n1) As[t]=Fs[b*400 + ROFFc[l1] + t];
    if(t<16*n2) Bs[t]=Fs[b*400 + ROFFc[l2] + t];
    if(t<nm*n1) sC[t]=g_cgcD[tr][t];
    __syncthreads();

    const int i=t>>4, j=t&15;
    const float2* Ai=&As[i*n1];
    const float2* Bj=&Bs[j*n2];

    float norm2=0.f;
    const int ffb = FFBASEc[l] + (b*nm)*K + chan;
    for(int mi=0;mi<nm;mi++){
        float aR=0.f, aI=0.f;
        for(int p=0;p<n1;p++){
            const float c = sC[mi*n1+p];       // wave-uniform (LDS broadcast)
            if(c!=0.f){
                const float2 av=Ai[p], bv=Bj[mi-p+d];
                const float pr = av.x*bv.x - av.y*bv.y;
                const float pi = av.x*bv.y + av.y*bv.x;
                aR=fmaf(c,pr,aR); aI=fmaf(c,pi,aI);
            }
        }
        g_FF[ffb + mi*K] = make_float2(aR,aI);
        norm2 = fmaf(aR,aR,norm2);
        norm2 = fmaf(aI,aI,norm2);
    }
    atomicAdd(&g_varsum[GBASEc[l]+chan], norm2);
}

// ---------------- kernel 3: finalize inv scale ----------------
__global__ void k_inv(){
    int c = blockIdx.x*256 + threadIdx.x;
    if(c>=NCH) return;
    int l = (c<1280)?0:(c<3328)?1:(c<5888)?2:(c<8448)?3:4;
    float denom = 256.0f*(float)(2*l+1);
    float v = g_varsum[c]/denom;
    g_inv[c] = 1.0f/(sqrtf(v)+1e-5f);
}

// ---------------- kernel 4: complex weight matmul (normalization folded into x) ----
// grid (5, 256): blockIdx.x = l, blockIdx.y = b.  256 threads = (o=t>>4, sub=t&15).
template<int L>
__device__ void mm_body(const float2* __restrict__ W2, float2* __restrict__ out,
                        int b, int t, float2* sh){
    constexpr int NM = 2*L+1;
    constexpr int K  = KL_t[L];
    constexpr int WO = WOFF_t[L];
    constexpr int FB = FFBASE_t[L];
    constexpr int GB = GBASE_t[L];
    constexpr int RO = ROFF_t[L];
    const int o=t>>4, sub=t&15;

    float2 acc[NM];
    #pragma unroll
    for(int m=0;m<NM;m++) acc[m]=make_float2(0.f,0.f);

    for(int c0=0;c0<K;c0+=256){
        // stage x-tile (256 channels x NM m's), normalization applied here
        const float invv = g_inv[GB + c0 + t];
        #pragma unroll
        for(int m=0;m<NM;m++){
            float2 v = g_FF[FB + (b*NM+m)*K + c0 + t];
            sh[m*256+t] = make_float2(v.x*invv, v.y*invv);
        }
        __syncthreads();
        #pragma unroll
        for(int k=0;k<16;k++){
            const int c2 = sub + (k<<4);      // strided: conflict-free LDS banks
            const float2 w = W2[WO + o*K + c0 + c2];
            #pragma unroll
            for(int m=0;m<NM;m++){
                const float2 x = sh[m*256+c2];
                acc[m].x = fmaf(w.x,x.x, fmaf(-w.y,x.y, acc[m].x));
                acc[m].y = fmaf(w.x,x.y, fmaf( w.y,x.x, acc[m].y));
            }
        }
        __syncthreads();
    }

    // reduce the 16 sub-partials per (o,m)
    #pragma unroll
    for(int m=0;m<NM;m++) sh[(m*16+o)*16+sub]=acc[m];
    __syncthreads();
    if(t<16*NM){
        const int o2=t/NM, m2=t%NM;
        float2 s=make_float2(0.f,0.f);
        for(int ss=0;ss<16;ss++){
            float2 v=sh[(m2*16+o2)*16+ss];
            s.x+=v.x; s.y+=v.y;
        }
        out[b*400 + RO + o2*NM + m2] = s;
    }
}

__global__ void __launch_bounds__(256) k_mm(const float2* __restrict__ W2,
                                            float2* __restrict__ out){
    __shared__ float2 sh[9*256];
    const int b=blockIdx.y, t=threadIdx.x;
    switch(blockIdx.x){
        case 0: mm_body<0>(W2,out,b,t,sh); break;
        case 1: mm_body<1>(W2,out,b,t,sh); break;
        case 2: mm_body<2>(W2,out,b,t,sh); break;
        case 3: mm_body<3>(W2,out,b,t,sh); break;
        case 4: mm_body<4>(W2,out,b,t,sh); break;
    }
}

// ---------------- launcher ----------------
extern "C" void kernel_launch(void* const* d_in, const int* in_sizes, int n_in,
                              void* d_out, int out_size, void* d_ws, size_t ws_size,
                              hipStream_t stream){
    const float2* Fs = (const float2*)d_in[0];   // [256,400,2] fp32
    const float2* W  = (const float2*)d_in[1];   // [172032,2]  fp32
    float2* out = (float2*)d_out;                // [256,400,2] fp32

    k_init<<<dim3(NTRI),128,0,stream>>>();
    k_cg <<<dim3(NTRI,B_SZ),256,0,stream>>>(Fs);
    k_inv<<<dim3((NCH+255)/256),256,0,stream>>>();
    k_mm <<<dim3(5,B_SZ),256,0,stream>>>(W,out);
}